// Round 3
// baseline (326.807 us; speedup 1.0000x reference)
//
#include <hip/hip_runtime.h>

#define D_MODEL 1024
#define NHEADS 16
#define HDIM 64
#define SEQ 2048
#define BATCH 2
#define M_TOTAL (BATCH * SEQ)   // 4096
#define N_QKV (3 * D_MODEL)     // 3072

typedef __attribute__((ext_vector_type(8))) short short8;
typedef __attribute__((ext_vector_type(4))) float f32x4;
typedef __attribute__((ext_vector_type(4))) unsigned short u16x4;
typedef unsigned short u16;

__device__ __forceinline__ u16 f2bf(float f) {
  union { float f; unsigned u; } v; v.f = f;
  unsigned u = v.u + 0x7fffu + ((v.u >> 16) & 1u);  // RNE
  return (u16)(u >> 16);
}

__device__ __forceinline__ void gload_lds16(const void* g, void* l) {
  __builtin_amdgcn_global_load_lds(
      (__attribute__((address_space(1))) void*)(g),
      (__attribute__((address_space(3))) void*)(l),
      16, 0, 0);
}

// ---------------- fp32 -> bf16 convert (vectorized) ----------------
__global__ void k_cvt_bf16(const float* __restrict__ src, u16* __restrict__ dst, int n4) {
  int i = blockIdx.x * blockDim.x + threadIdx.x;
  if (i >= n4) return;
  const float4 v = reinterpret_cast<const float4*>(src)[i];
  u16x4 o;
  o.x = f2bf(v.x); o.y = f2bf(v.y); o.z = f2bf(v.z); o.w = f2bf(v.w);
  reinterpret_cast<u16x4*>(dst)[i] = o;
}

// ---------------- transpose + convert: src[R][C] f32 -> dst[C][R] bf16 ----------------
__global__ void k_transpose_bf16(const float* __restrict__ src, u16* __restrict__ dst, int R, int C) {
  __shared__ float tile[32][33];
  const int bx = blockIdx.x * 32;  // col base in src
  const int by = blockIdx.y * 32;  // row base in src
  const int tx = threadIdx.x, ty = threadIdx.y;
  #pragma unroll
  for (int i = ty; i < 32; i += 8) tile[i][tx] = src[(size_t)(by + i) * C + bx + tx];
  __syncthreads();
  #pragma unroll
  for (int i = ty; i < 32; i += 8) dst[(size_t)(bx + i) * R + by + tx] = f2bf(tile[tx][i]);
}

// ---------------- shared GEMM core: 128x128 tile, BK=32, 4 waves ----------------
// A: [M][K] bf16 row-major; Bt: [N][K] bf16 row-major (i.e. B transposed)
template <int K>
__device__ __forceinline__ void gemm_core(const u16* __restrict__ A, const u16* __restrict__ Bt,
                                          int m0, int n0, u16* As, u16* Bs, f32x4 acc[4][4]) {
  const int tid = threadIdx.x;
  const int lane = tid & 63;
  const int lr = lane & 15, lg = lane >> 4;
  const int wr = ((tid >> 7) & 1) * 64;
  const int wc = ((tid >> 6) & 1) * 64;
  for (int kt = 0; kt < K; kt += 32) {
    #pragma unroll
    for (int r = 0; r < 2; ++r) {
      const int off = r * 4096 + tid * 16;         // LDS byte offset (linear)
      const int row = off >> 6, colb = off & 63;   // 32 bf16 cols = 64B per row
      gload_lds16((const char*)A + ((size_t)(m0 + row) * K + kt) * 2 + colb, (char*)As + off);
      gload_lds16((const char*)Bt + ((size_t)(n0 + row) * K + kt) * 2 + colb, (char*)Bs + off);
    }
    __syncthreads();
    short8 a[4], b[4];
    #pragma unroll
    for (int i = 0; i < 4; ++i) a[i] = *(const short8*)&As[(wr + i * 16 + lr) * 32 + lg * 8];
    #pragma unroll
    for (int i = 0; i < 4; ++i) b[i] = *(const short8*)&Bs[(wc + i * 16 + lr) * 32 + lg * 8];
    #pragma unroll
    for (int mi = 0; mi < 4; ++mi)
      #pragma unroll
      for (int ni = 0; ni < 4; ++ni)
        acc[mi][ni] = __builtin_amdgcn_mfma_f32_16x16x32_bf16(a[mi], b[ni], acc[mi][ni], 0, 0, 0);
    __syncthreads();
  }
}

// ---------------- GEMM1: qkv = x @ w_qkv + b_qkv, scatter to q/k/v head layout ----------------
__global__ __launch_bounds__(256) void k_gemm_qkv(const u16* __restrict__ A, const u16* __restrict__ Bt,
                                                  const float* __restrict__ bias,
                                                  u16* __restrict__ qb, u16* __restrict__ kb,
                                                  u16* __restrict__ vb) {
  __shared__ u16 As[128 * 32];
  __shared__ u16 Bs[128 * 32];
  f32x4 acc[4][4] = {};
  const int m0 = blockIdx.x * 128, n0 = blockIdx.y * 128;
  gemm_core<D_MODEL>(A, Bt, m0, n0, As, Bs, acc);
  const int lane = threadIdx.x & 63, lr = lane & 15, lg = lane >> 4;
  const int wr = ((threadIdx.x >> 7) & 1) * 64, wc = ((threadIdx.x >> 6) & 1) * 64;
  #pragma unroll
  for (int ni = 0; ni < 4; ++ni) {
    const int col = n0 + wc + ni * 16 + lr;
    const float bv = bias[col];
    const int which = col >> 10;
    const int h = (col >> 6) & 15;
    const int d = col & 63;
    #pragma unroll
    for (int mi = 0; mi < 4; ++mi) {
      #pragma unroll
      for (int j = 0; j < 4; ++j) {
        const int rw = m0 + wr + mi * 16 + lg * 4 + j;
        const int bb = rw >> 11, t = rw & (SEQ - 1);
        const u16 val = f2bf(acc[mi][ni][j] + bv);
        const int bh = bb * NHEADS + h;
        if (which == 0)      qb[((size_t)bh * SEQ + t) * HDIM + d] = val;
        else if (which == 1) kb[((size_t)bh * SEQ + t) * HDIM + d] = val;
        else                 vb[((size_t)bh * HDIM + d) * SEQ + t] = val;  // V stored transposed [d][t]
      }
    }
  }
}

// ---------------- GEMM2: out = attn @ w_out + b_out (fp32 output) ----------------
__global__ __launch_bounds__(256) void k_gemm_out(const u16* __restrict__ A, const u16* __restrict__ Bt,
                                                  const float* __restrict__ bias,
                                                  float* __restrict__ out) {
  __shared__ u16 As[128 * 32];
  __shared__ u16 Bs[128 * 32];
  f32x4 acc[4][4] = {};
  const int m0 = blockIdx.x * 128, n0 = blockIdx.y * 128;
  gemm_core<D_MODEL>(A, Bt, m0, n0, As, Bs, acc);
  const int lane = threadIdx.x & 63, lr = lane & 15, lg = lane >> 4;
  const int wr = ((threadIdx.x >> 7) & 1) * 64, wc = ((threadIdx.x >> 6) & 1) * 64;
  #pragma unroll
  for (int ni = 0; ni < 4; ++ni) {
    const int col = n0 + wc + ni * 16 + lr;
    const float bv = bias[col];
    #pragma unroll
    for (int mi = 0; mi < 4; ++mi) {
      #pragma unroll
      for (int j = 0; j < 4; ++j) {
        const int rw = m0 + wr + mi * 16 + lg * 4 + j;
        out[(size_t)rw * D_MODEL + col] = acc[mi][ni][j] + bv;
      }
    }
  }
}

// ---------------- flash attention (causal), 4 waves x 32 q-rows, KV tiles of 64 ----------------
__global__ __launch_bounds__(256) void k_attn(const u16* __restrict__ qb, const u16* __restrict__ kb,
                                              const u16* __restrict__ vb, u16* __restrict__ attn) {
  __shared__ u16 Pl[4][32 * 64];  // per-wave P buffer (XOR-swizzled), 4KB each
  const int tid = threadIdx.x, lane = tid & 63, wid = tid >> 6;
  const int lr = lane & 15, lg = lane >> 4;
  const int bh = blockIdx.y, b = bh >> 4, h = bh & 15;
  const int q0 = blockIdx.x * 128;
  const int qw = q0 + wid * 32;  // this wave's 32 q-rows
  const u16* Q = qb + (size_t)bh * SEQ * HDIM;
  const u16* Kp = kb + (size_t)bh * SEQ * HDIM;
  const u16* Vp = vb + (size_t)bh * HDIM * SEQ;  // [64][2048]
  u16* Pw = &Pl[wid][0];

  // Q fragments in registers: A-layout, rows qw + mi*16 + lr, k = ks*32 + lg*8
  short8 aq[2][2];
  #pragma unroll
  for (int mi = 0; mi < 2; ++mi)
    #pragma unroll
    for (int ks = 0; ks < 2; ++ks)
      aq[mi][ks] = *(const short8*)&Q[(size_t)(qw + mi * 16 + lr) * HDIM + ks * 32 + lg * 8];

  f32x4 acc[2][4] = {};
  float mrun[2][4], lrun[2][4];
  #pragma unroll
  for (int mi = 0; mi < 2; ++mi)
    #pragma unroll
    for (int j = 0; j < 4; ++j) { mrun[mi][j] = -3e38f; lrun[mi][j] = 0.f; }

  const float sc = 0.125f * 1.44269504089f;  // SCALE * log2(e)
  const int ntile = q0 / 64 + 2;             // covers s up to q0+127

  for (int st = 0; st < ntile; ++st) {
    const int s0 = st * 64;
    if (s0 > qw + 31) break;  // this wave's rows are all masked from here on

    // S = Q K^T  (D[q][s])
    f32x4 s[2][4] = {};
    #pragma unroll
    for (int ks = 0; ks < 2; ++ks) {
      #pragma unroll
      for (int ni = 0; ni < 4; ++ni) {
        const short8 kf = *(const short8*)&Kp[(size_t)(s0 + ni * 16 + lr) * HDIM + ks * 32 + lg * 8];
        #pragma unroll
        for (int mi = 0; mi < 2; ++mi)
          s[mi][ni] = __builtin_amdgcn_mfma_f32_16x16x32_bf16(aq[mi][ks], kf, s[mi][ni], 0, 0, 0);
      }
    }

    // scale + causal mask (in log2 domain)
    const bool need_mask = (s0 + 63 > qw);
    #pragma unroll
    for (int mi = 0; mi < 2; ++mi)
      #pragma unroll
      for (int ni = 0; ni < 4; ++ni)
        #pragma unroll
        for (int j = 0; j < 4; ++j) {
          float v = s[mi][ni][j] * sc;
          if (need_mask) {
            const int qq = qw + mi * 16 + lg * 4 + j;
            const int ss = s0 + ni * 16 + lr;
            v = (ss > qq) ? -1e30f : v;
          }
          s[mi][ni][j] = v;
        }

    // online softmax: row = (lg*4 + j); reduce across 16-lane group + 4 ni frags
    #pragma unroll
    for (int mi = 0; mi < 2; ++mi) {
      #pragma unroll
      for (int j = 0; j < 4; ++j) {
        float pm = fmaxf(fmaxf(s[mi][0][j], s[mi][1][j]), fmaxf(s[mi][2][j], s[mi][3][j]));
        pm = fmaxf(pm, __shfl_xor(pm, 1));
        pm = fmaxf(pm, __shfl_xor(pm, 2));
        pm = fmaxf(pm, __shfl_xor(pm, 4));
        pm = fmaxf(pm, __shfl_xor(pm, 8));
        const float nm = fmaxf(mrun[mi][j], pm);
        const float resc = exp2f(mrun[mi][j] - nm);
        mrun[mi][j] = nm;
        float rs = 0.f;
        #pragma unroll
        for (int ni = 0; ni < 4; ++ni) {
          const float e = exp2f(s[mi][ni][j] - nm);
          s[mi][ni][j] = e;
          rs += e;
        }
        rs += __shfl_xor(rs, 1);
        rs += __shfl_xor(rs, 2);
        rs += __shfl_xor(rs, 4);
        rs += __shfl_xor(rs, 8);
        lrun[mi][j] = lrun[mi][j] * resc + rs;
        #pragma unroll
        for (int ni = 0; ni < 4; ++ni) acc[mi][ni][j] *= resc;
      }
    }

    // write P (bf16) to wave-private LDS, XOR-swizzled to kill 128B-stride conflicts
    #pragma unroll
    for (int mi = 0; mi < 2; ++mi)
      #pragma unroll
      for (int ni = 0; ni < 4; ++ni)
        #pragma unroll
        for (int j = 0; j < 4; ++j) {
          const int row = mi * 16 + lg * 4 + j;
          const int col = ni * 16 + lr;
          const int byte = (row * 128 + col * 2) ^ ((row & 7) << 4);
          *(u16*)((char*)Pw + byte) = f2bf(s[mi][ni][j]);
        }

    // O += P @ V   (A-frag of P from LDS; B-frag of V from transposed global V)
    #pragma unroll
    for (int ks = 0; ks < 2; ++ks) {
      short8 pa[2];
      #pragma unroll
      for (int mi = 0; mi < 2; ++mi) {
        const int row = mi * 16 + lr;
        const int byte = (row * 128 + ks * 64 + lg * 16) ^ ((row & 7) << 4);
        pa[mi] = *(const short8*)((const char*)Pw + byte);
      }
      #pragma unroll
      for (int ni = 0; ni < 4; ++ni) {
        const short8 vf = *(const short8*)&Vp[(size_t)(ni * 16 + lr) * SEQ + s0 + ks * 32 + lg * 8];
        #pragma unroll
        for (int mi = 0; mi < 2; ++mi)
          acc[mi][ni] = __builtin_amdgcn_mfma_f32_16x16x32_bf16(pa[mi], vf, acc[mi][ni], 0, 0, 0);
      }
    }
  }

  // epilogue: O /= l, write [b][t][h*64+d] bf16
  #pragma unroll
  for (int mi = 0; mi < 2; ++mi)
    #pragma unroll
    for (int j = 0; j < 4; ++j) {
      const float inv = 1.f / lrun[mi][j];
      const int t = qw + mi * 16 + lg * 4 + j;
      #pragma unroll
      for (int ni = 0; ni < 4; ++ni) {
        const int col = h * HDIM + ni * 16 + lr;
        attn[((size_t)b * SEQ + t) * D_MODEL + col] = f2bf(acc[mi][ni][j] * inv);
      }
    }
}

extern "C" void kernel_launch(void* const* d_in, const int* in_sizes, int n_in,
                              void* d_out, int out_size, void* d_ws, size_t ws_size,
                              hipStream_t stream) {
  const float* x     = (const float*)d_in[0];
  const float* w_qkv = (const float*)d_in[1];
  const float* b_qkv = (const float*)d_in[2];
  const float* w_out = (const float*)d_in[3];
  const float* b_out = (const float*)d_in[4];
  float* out = (float*)d_out;

  char* ws = (char*)d_ws;
  u16* xb    = (u16*)(ws);                           // 8 MB  [4096][1024]
  u16* wqkvT = (u16*)(ws + ((size_t)8 << 20));       // 6 MB  [3072][1024]
  u16* woutT = (u16*)(ws + ((size_t)14 << 20));      // 2 MB  [1024][1024]
  u16* qbuf  = (u16*)(ws + ((size_t)16 << 20));      // 8 MB  [32][2048][64]
  u16* kbuf  = (u16*)(ws + ((size_t)24 << 20));      // 8 MB  [32][2048][64]
  u16* vbuf  = (u16*)(ws + ((size_t)32 << 20));      // 8 MB  [32][64][2048]
  u16* attn  = (u16*)(ws + ((size_t)40 << 20));      // 8 MB  [4096][1024]  (total 48 MB)

  k_cvt_bf16<<<(M_TOTAL * D_MODEL / 4 + 255) / 256, 256, 0, stream>>>(x, xb, M_TOTAL * D_MODEL / 4);
  k_transpose_bf16<<<dim3(N_QKV / 32, D_MODEL / 32), dim3(32, 8), 0, stream>>>(w_qkv, wqkvT, D_MODEL, N_QKV);
  k_transpose_bf16<<<dim3(D_MODEL / 32, D_MODEL / 32), dim3(32, 8), 0, stream>>>(w_out, woutT, D_MODEL, D_MODEL);
  k_gemm_qkv<<<dim3(M_TOTAL / 128, N_QKV / 128), 256, 0, stream>>>(xb, wqkvT, b_qkv, qbuf, kbuf, vbuf);
  k_attn<<<dim3(SEQ / 128, BATCH * NHEADS), 256, 0, stream>>>(qbuf, kbuf, vbuf, attn);
  k_gemm_out<<<dim3(M_TOTAL / 128, D_MODEL / 128), 256, 0, stream>>>(attn, woutT, b_out, out);
}